// Round 1
// baseline (174.777 us; speedup 1.0000x reference)
//
#include <hip/hip_runtime.h>
#include <math.h>

// NoisyEmbedding: argmax_j( cos_sim(w[ids[i]], w[j]) + 20 * gumbel[i][j] ) -> gather w[argmax]
//
// Key insight: sims are in [-1,1] so only indices with gumbel g within 0.1 of the
// row max of g can win the argmax (20*0.1 = 2 = max sim spread). g = -log(-log u)
// is monotone in u, so max-finding and thresholding happen in the u-domain with
// no transcendentals in the streaming pass. We collect a chunk-local superset of
// the candidate set (threshold vs. the CHUNK max, margin 0.1001), then rescore
// candidates exactly in f32 and argmax with first-index tie-break (jnp.argmax).

constexpr int V  = 50257;
constexpr int D  = 768;
constexpr int BT = 2048;
constexpr int CHUNK  = 2048;
constexpr int NCHUNK = (V + CHUNK - 1) / CHUNK;  // 25
constexpr int CAP    = 256;                      // per-row candidate capacity (E[count]~30)
constexpr float KPOW = 1.1052847f;               // expf(0.1001): u-domain threshold exponent
constexpr float TWO_OVER_EPS = 20.0f;

// --- K0: inverse L2 norms for all vocab rows. One wave (64 lanes) per row. ---
__global__ __launch_bounds__(256) void k_invnorm(const float* __restrict__ w,
                                                 float* __restrict__ invn) {
  int wid  = threadIdx.x >> 6;
  int lane = threadIdx.x & 63;
  int row  = blockIdx.x * 4 + wid;
  if (row >= V) return;
  const float4* p = reinterpret_cast<const float4*>(w + (size_t)row * D);
  float s = 0.f;
#pragma unroll
  for (int k = 0; k < 3; ++k) {           // 3 * 64 lanes * 4 floats = 768
    float4 v = p[k * 64 + lane];
    s += v.x * v.x + v.y * v.y + v.z * v.z + v.w * v.w;
  }
#pragma unroll
  for (int off = 32; off > 0; off >>= 1) s += __shfl_down(s, off, 64);
  if (lane == 0) invn[row] = 1.0f / fmaxf(sqrtf(s), 1e-12f);
}

// --- K1: stream gumbel_u, per (row, chunk): block max in u-domain, filter
//         u >= u_cmax^KPOW into per-row candidate list. ---
__global__ __launch_bounds__(256) void k_gumbel_scan(const float* __restrict__ gum,
                                                     int* __restrict__ cnt,
                                                     int* __restrict__ cidx,
                                                     float* __restrict__ cu) {
  int row  = blockIdx.x / NCHUNK;
  int c    = blockIdx.x % NCHUNK;
  int base = c * CHUNK;
  const float* g = gum + (size_t)row * V;
  int tid = threadIdx.x;

  float u[8];
#pragma unroll
  for (int k = 0; k < 8; ++k) {
    int idx = base + k * 256 + tid;       // coalesced dword loads
    u[k] = (idx < V) ? g[idx] : -1.0f;
  }
  float m = u[0];
#pragma unroll
  for (int k = 1; k < 8; ++k) m = fmaxf(m, u[k]);
#pragma unroll
  for (int off = 32; off > 0; off >>= 1) m = fmaxf(m, __shfl_down(m, off, 64));

  __shared__ float wmax[4];
  __shared__ float s_ut;
  int lane = tid & 63, wid = tid >> 6;
  if (lane == 0) wmax[wid] = m;
  __syncthreads();
  if (tid == 0) {
    float bm = fmaxf(fmaxf(wmax[0], wmax[1]), fmaxf(wmax[2], wmax[3]));
    // g >= g_cmax - 0.1001  <=>  u >= u_cmax^exp(0.1001)   (u in (0,1])
    s_ut = expf(KPOW * logf(bm));
  }
  __syncthreads();
  float ut = s_ut;
#pragma unroll
  for (int k = 0; k < 8; ++k) {
    if (u[k] >= ut) {                      // OOB lanes hold -1 < ut, never pass
      int slot = atomicAdd(&cnt[row], 1);
      if (slot < CAP) {
        cidx[row * CAP + slot] = base + k * 256 + tid;
        cu[row * CAP + slot]   = u[k];
      }
    }
  }
}

// --- K2: per row, exact f32 rescore of candidates + argmax + output gather. ---
__global__ __launch_bounds__(256) void k_score(const float* __restrict__ w,
                                               const int* __restrict__ ids,
                                               const float* __restrict__ invn,
                                               const int* __restrict__ cnt,
                                               const int* __restrict__ cidx,
                                               const float* __restrict__ cu,
                                               float* __restrict__ out) {
  __shared__ __align__(16) float q[D];
  __shared__ float sc[CAP];
  __shared__ int s_sel;
  int row = blockIdx.x;
  int tid = threadIdx.x;
  int qid = ids[row];
#pragma unroll
  for (int k = 0; k < 3; ++k)
    q[k * 256 + tid] = w[(size_t)qid * D + k * 256 + tid];
  __syncthreads();

  int n = min(cnt[row], CAP);
  float invq = invn[qid];
  int lane = tid & 63, wid = tid >> 6;

  for (int cI = wid; cI < n; cI += 4) {    // one wave per candidate
    int j = cidx[row * CAP + cI];
    const float4* p  = reinterpret_cast<const float4*>(w + (size_t)j * D);
    const float4* qp = reinterpret_cast<const float4*>(q);
    float dot = 0.f;
#pragma unroll
    for (int k = 0; k < 3; ++k) {
      float4 a = p[k * 64 + lane];
      float4 b = qp[k * 64 + lane];
      dot += a.x * b.x + a.y * b.y + a.z * b.z + a.w * b.w;
    }
#pragma unroll
    for (int off = 32; off > 0; off >>= 1) dot += __shfl_down(dot, off, 64);
    if (lane == 0) {
      float uu = cu[row * CAP + cI];
      float gg = -logf(-logf(uu));         // matches ref formula; inf-safe
      sc[cI] = invq * invn[j] * dot + TWO_OVER_EPS * gg;
    }
  }
  __syncthreads();

  if (wid == 0) {                          // lexicographic argmax: (score desc, idx asc)
    float bs = -INFINITY;
    int bj = 0x7fffffff;
    for (int cI = lane; cI < n; cI += 64) {
      float s = sc[cI];
      int j = cidx[row * CAP + cI];
      if (s > bs || (s == bs && j < bj)) { bs = s; bj = j; }
    }
#pragma unroll
    for (int off = 32; off > 0; off >>= 1) {
      float os = __shfl_down(bs, off, 64);
      int   oj = __shfl_down(bj, off, 64);
      if (os > bs || (os == bs && oj < bj)) { bs = os; bj = oj; }
    }
    if (lane == 0) s_sel = bj;
  }
  __syncthreads();

  int sel = s_sel;
#pragma unroll
  for (int k = 0; k < 3; ++k)
    out[(size_t)row * D + k * 256 + tid] = w[(size_t)sel * D + k * 256 + tid];
}

extern "C" void kernel_launch(void* const* d_in, const int* in_sizes, int n_in,
                              void* d_out, int out_size, void* d_ws, size_t ws_size,
                              hipStream_t stream) {
  const int*   ids = (const int*)d_in[0];    // input_ids (B*T)
  const float* w   = (const float*)d_in[1];  // weight (V*D)
  const float* gum = (const float*)d_in[2];  // gumbel_u (BT*V)
  float* out = (float*)d_out;

  char* ws = (char*)d_ws;
  float* invn = (float*)ws;                                      // V floats (pad to 51200)
  int*   cnt  = (int*)(ws + 51200 * 4);                          // BT ints
  int*   cidx = (int*)(ws + 51200 * 4 + BT * 4);                 // BT*CAP ints
  float* cu   = (float*)(ws + 51200 * 4 + BT * 4 + BT * CAP * 4);// BT*CAP floats
  // total ws use ~4.4 MB

  hipMemsetAsync(cnt, 0, BT * sizeof(int), stream);  // must reset each call (graph replays)
  k_invnorm<<<(V + 3) / 4, 256, 0, stream>>>(w, invn);
  k_gumbel_scan<<<BT * NCHUNK, 256, 0, stream>>>(gum, cnt, cidx, cu);
  k_score<<<BT, 256, 0, stream>>>(w, ids, invn, cnt, cidx, cu, out);
}

// Round 3
// 90.243 us; speedup vs baseline: 1.9367x; 1.9367x over previous
//
#include <hip/hip_runtime.h>
#include <math.h>

// NoisyEmbedding: argmax_j( cos_sim(w[ids[i]], w[j]) + 20*gumbel[i][j] ) -> gather w[argmax]
//
// sims span <= 2, so only j with gumbel g within 0.1 of the row max can win
// (20*0.1 = 2). g = -log(-log u) is monotone in u -> stream gumbel_u once in
// the u-domain (no transcendentals), keep per-chunk survivors within 0.1001 of
// the chunk max (superset of the needed set), then rescore survivors exactly
// in f32 and argmax with first-index tie-break (matches jnp.argmax).
//
// Flat-space aligned float4 chunks (8192 elems; a chunk straddles <=1 row
// boundary -> two segment maxima), norms folded into k_score's existing
// loads, nontemporal gumbel loads (ext_vector_type for the builtin).

constexpr int V  = 50257;
constexpr int D  = 768;
constexpr int BT = 2048;
constexpr long TOTAL = (long)BT * V;            // 102,926,336 elements (fits int32)
constexpr int ITOTAL = (int)TOTAL;
constexpr int NF4    = ITOTAL >> 2;             // total float4s (TOTAL % 4 == 0)
constexpr int CHUNK  = 8192;                    // elements per block
constexpr int NBLK   = (ITOTAL + CHUNK - 1) / CHUNK;  // 12565
constexpr int CAP    = 128;                     // per-row candidate capacity (E ~ 7)
constexpr float KPOW = 1.1052847f;              // expf(0.1001): u-domain exponent
constexpr float TWO_OVER_EPS = 20.0f;

typedef float f32x4 __attribute__((ext_vector_type(4)));

// --- K1: stream gumbel_u (flat, aligned float4), per block: segment maxima
//         (low/high of the <=1 row boundary), filter u >= u_segmax^KPOW. ---
__global__ __launch_bounds__(256) void k_scan(const float* __restrict__ gum,
                                              int* __restrict__ cnt,
                                              int* __restrict__ cidx,
                                              float* __restrict__ cu) {
  int tid   = threadIdx.x;
  int start = blockIdx.x * CHUNK;               // < 2^31
  int row0  = start / V;                        // magic-mul, compile-time V
  int b     = (row0 + 1) * V;                   // first element of next row

  const f32x4* g4 = reinterpret_cast<const f32x4*>(gum);
  int f4base = start >> 2;

  f32x4 v[8];
#pragma unroll
  for (int k = 0; k < 8; ++k) {                 // 8 coalesced 16B rounds
    int fi = f4base + k * 256 + tid;
    if (fi < NF4) v[k] = __builtin_nontemporal_load(&g4[fi]);
    else          v[k] = (f32x4){-1.f, -1.f, -1.f, -1.f};
  }

  // per-thread segment maxima (row boundary b may split a float4: V is odd)
  float mlo = -1.f, mhi = -1.f;
#pragma unroll
  for (int k = 0; k < 8; ++k) {
    int e0 = (f4base + k * 256 + tid) << 2;
#pragma unroll
    for (int j = 0; j < 4; ++j) {
      if (e0 + j < b) mlo = fmaxf(mlo, v[k][j]);
      else            mhi = fmaxf(mhi, v[k][j]);
    }
  }
  int lane = tid & 63, wid = tid >> 6;
#pragma unroll
  for (int off = 32; off > 0; off >>= 1) {
    mlo = fmaxf(mlo, __shfl_down(mlo, off, 64));
    mhi = fmaxf(mhi, __shfl_down(mhi, off, 64));
  }
  __shared__ float slo[4], shi[4];
  __shared__ float s_tlo, s_thi;
  if (lane == 0) { slo[wid] = mlo; shi[wid] = mhi; }
  __syncthreads();
  if (tid == 0) {
    float a = fmaxf(fmaxf(slo[0], slo[1]), fmaxf(slo[2], slo[3]));
    float c = fmaxf(fmaxf(shi[0], shi[1]), fmaxf(shi[2], shi[3]));
    // g >= g_segmax - 0.1001  <=>  u >= u_segmax^KPOW.  Empty segment:
    // max = -1 -> logf(-1) = NaN -> threshold NaN -> all compares false.
    s_tlo = expf(KPOW * logf(a));
    s_thi = expf(KPOW * logf(c));
  }
  __syncthreads();
  float tlo = s_tlo, thi = s_thi;

#pragma unroll
  for (int k = 0; k < 8; ++k) {
    int e0 = (f4base + k * 256 + tid) << 2;
#pragma unroll
    for (int j = 0; j < 4; ++j) {
      int idx = e0 + j;
      bool lo = idx < b;
      float t = lo ? tlo : thi;
      float uu = v[k][j];
      if (uu >= t) {                             // OOB lanes hold -1, never pass
        int row = lo ? row0 : row0 + 1;
        int slot = atomicAdd(&cnt[row], 1);
        if (slot < CAP) {
          cidx[row * CAP + slot] = idx - row * V;
          cu[row * CAP + slot]   = uu;
        }
      }
    }
  }
}

// --- K2: per row, exact f32 rescore of candidates (norms computed on the fly
//         from the loads we already do) + lexicographic argmax + gather. ---
__global__ __launch_bounds__(256) void k_score(const float* __restrict__ w,
                                               const int* __restrict__ ids,
                                               const int* __restrict__ cnt,
                                               const int* __restrict__ cidx,
                                               const float* __restrict__ cu,
                                               float* __restrict__ out) {
  __shared__ __align__(16) float q[D];
  __shared__ float sc[CAP];
  __shared__ float s_red[4];
  __shared__ float s_invq;
  __shared__ int s_sel;
  int row = blockIdx.x;
  int tid = threadIdx.x;
  int lane = tid & 63, wid = tid >> 6;
  int qid = ids[row];

  float qs = 0.f;
#pragma unroll
  for (int k = 0; k < 3; ++k) {
    float x = w[(size_t)qid * D + k * 256 + tid];
    q[k * 256 + tid] = x;
    qs += x * x;
  }
#pragma unroll
  for (int off = 32; off > 0; off >>= 1) qs += __shfl_down(qs, off, 64);
  if (lane == 0) s_red[wid] = qs;
  __syncthreads();
  if (tid == 0)
    s_invq = 1.0f / fmaxf(sqrtf(s_red[0] + s_red[1] + s_red[2] + s_red[3]), 1e-12f);
  __syncthreads();

  int n = min(cnt[row], CAP);
  float invq = s_invq;

  for (int cI = wid; cI < n; cI += 4) {          // one wave per candidate
    int j = cidx[row * CAP + cI];
    const float4* p  = reinterpret_cast<const float4*>(w + (size_t)j * D);
    const float4* qp = reinterpret_cast<const float4*>(q);
    float dot = 0.f, n2 = 0.f;
#pragma unroll
    for (int k = 0; k < 3; ++k) {
      float4 a = p[k * 64 + lane];
      float4 bq = qp[k * 64 + lane];
      dot += a.x * bq.x + a.y * bq.y + a.z * bq.z + a.w * bq.w;
      n2  += a.x * a.x  + a.y * a.y  + a.z * a.z  + a.w * a.w;
    }
#pragma unroll
    for (int off = 32; off > 0; off >>= 1) {
      dot += __shfl_down(dot, off, 64);
      n2  += __shfl_down(n2,  off, 64);
    }
    if (lane == 0) {
      float invj = 1.0f / fmaxf(sqrtf(n2), 1e-12f);
      float uu = cu[row * CAP + cI];
      sc[cI] = invq * invj * dot + TWO_OVER_EPS * (-logf(-logf(uu)));
    }
  }
  __syncthreads();

  if (wid == 0) {                                // argmax: (score desc, idx asc)
    float bs = -INFINITY;
    int bj = 0x7fffffff;
    for (int cI = lane; cI < n; cI += 64) {
      float s = sc[cI];
      int j = cidx[row * CAP + cI];
      if (s > bs || (s == bs && j < bj)) { bs = s; bj = j; }
    }
#pragma unroll
    for (int off = 32; off > 0; off >>= 1) {
      float os = __shfl_down(bs, off, 64);
      int   oj = __shfl_down(bj, off, 64);
      if (os > bs || (os == bs && oj < bj)) { bs = os; bj = oj; }
    }
    if (lane == 0) s_sel = bj;
  }
  __syncthreads();

  int sel = s_sel;
#pragma unroll
  for (int k = 0; k < 3; ++k)
    out[(size_t)row * D + k * 256 + tid] = w[(size_t)sel * D + k * 256 + tid];
}

extern "C" void kernel_launch(void* const* d_in, const int* in_sizes, int n_in,
                              void* d_out, int out_size, void* d_ws, size_t ws_size,
                              hipStream_t stream) {
  const int*   ids = (const int*)d_in[0];    // input_ids (B*T)
  const float* w   = (const float*)d_in[1];  // weight (V*D)
  const float* gum = (const float*)d_in[2];  // gumbel_u (BT*V)
  float* out = (float*)d_out;

  char* ws = (char*)d_ws;
  int*   cnt  = (int*)ws;                              // BT ints
  int*   cidx = (int*)(ws + BT * 4);                   // BT*CAP ints
  float* cu   = (float*)(ws + BT * 4 + BT * CAP * 4);  // BT*CAP floats
  // ~2.1 MB of ws

  (void)hipMemsetAsync(cnt, 0, BT * sizeof(int), stream);  // reset per call (graph replay)
  k_scan<<<NBLK, 256, 0, stream>>>(gum, cnt, cidx, cu);
  k_score<<<BT, 256, 0, stream>>>(w, ids, cnt, cidx, cu, out);
}